// Round 8
// baseline (1171.801 us; speedup 1.0000x reference)
//
#include <hip/hip_runtime.h>

#define DT 0.1f

typedef float v2f __attribute__((ext_vector_type(2)));

// Guaranteed packed fp32 FMA (VOP3P; operands are 64-bit VGPR pairs).
__device__ __forceinline__ v2f pk_fma(v2f a, v2f b, v2f c) {
    v2f d;
    asm("v_pk_fma_f32 %0, %1, %2, %3" : "=v"(d) : "v"(a), "v"(b), "v"(c));
    return d;
}

// DPP quad reduce: 0xB1 = quad_perm(1,0,3,2) (xor1), 0x4E = quad_perm(2,3,0,1) (xor2).
template <int CTRL>
__device__ __forceinline__ float dpp_add(float x) {
    int v = __builtin_amdgcn_mov_dpp(__float_as_int(x), CTRL, 0xf, 0xf, true);
    return x + __int_as_float(v);
}

// Quad (4 lanes) owns elements {e0 = qd, e1 = qd + batch/2}; lane p = tid&3 owns
// hidden units [p*64, (p+1)*64). Weights live in LDS and are read per step as
// 16-lane-broadcast ds_read_b128 (4 distinct addresses, bank-staggered by the
// 1056B p-block stride -> conflict-free). Rounds 3-7 proved thread-private
// weight arrays always get AGPR-parked (+per-use copies); LDS broadcast makes
// per-thread state ~50 VGPRs so there is nothing to park.
__global__ __launch_bounds__(256, 2) void waterbalance(
    const float* __restrict__ inflows, const float* __restrict__ storage0,
    const float* __restrict__ W1, const float* __restrict__ b1,
    const float* __restrict__ W2, const float* __restrict__ b2,
    float* __restrict__ out_storages, float* __restrict__ out_outflows,
    int iters, int batch, int hidden)
{
    // Per-p-block plane layout (floats): [0,64)=wx, [64,128)=wy, [128,192)=wb,
    // [192,256)=w2, [256,264)=pad. Stride 264 floats = 1056 B (bank stagger).
    __shared__ __align__(16) float sm[4][264];

    {   // Stage weights once: thread j owns hidden unit j.
        const int j = threadIdx.x;
        if (j < hidden) {
            const int p = j >> 6, idx = j & 63;
            sm[p][idx]        = W1[j];            // W1[0][j]
            sm[p][64 + idx]   = W1[hidden + j];   // W1[1][j]
            sm[p][128 + idx]  = b1[j];
            sm[p][192 + idx]  = W2[j];
        }
    }
    __syncthreads();

    const int tid = blockIdx.x * blockDim.x + threadIdx.x;
    const int qd  = tid >> 2;          // quad id = element e0
    const int p   = tid & 3;           // unit-block within element
    const int half = batch >> 1;
    if (qd >= half) return;

    const int e0 = qd, e1 = qd + half;

    const float4* __restrict__ wxp = (const float4*)&sm[p][0];
    const float4* __restrict__ wyp = (const float4*)&sm[p][64];
    const float4* __restrict__ wbp = (const float4*)&sm[p][128];
    const float4* __restrict__ w2p = (const float4*)&sm[p][192];

    const float b2v = b2[0];

    float sA = storage0[e0];
    float sB = storage0[e1];
    if (p == 0) { out_storages[e0] = sA; out_storages[e1] = sB; }

    const float* __restrict__ inA = inflows + e0;
    const float* __restrict__ inB = inflows + e1;
    float* __restrict__ poA = out_outflows + e0;
    float* __restrict__ poB = out_outflows + e1;
    float* __restrict__ psA = out_storages + (size_t)batch + e0;
    float* __restrict__ psB = out_storages + (size_t)batch + e1;

    const int nchunk = iters >> 2;
    const int tail_start = nchunk << 2;

    float bufA[4], bufB[4];
    #pragma unroll
    for (int r = 0; r < 4; ++r) {
        bufA[r] = inA[(size_t)r * batch];
        bufB[r] = inB[(size_t)r * batch];
    }

    for (int c = 0; c < nchunk; ++c) {
        float nbA[4], nbB[4];
        if (c + 1 < nchunk) {
            const float* qA = inA + (size_t)(c + 1) * 4 * batch;
            const float* qB = inB + (size_t)(c + 1) * 4 * batch;
            #pragma unroll
            for (int r = 0; r < 4; ++r) { nbA[r] = qA[(size_t)r * batch]; nbB[r] = qB[(size_t)r * batch]; }
        } else {
            #pragma unroll
            for (int r = 0; r < 4; ++r) { nbA[r] = 0.0f; nbB[r] = 0.0f; }
        }

        #pragma unroll
        for (int r = 0; r < 4; ++r) {
            const float ia = bufA[r], ib = bufB[r];
            const v2f inA2 = (v2f){ia, ia}, sA2 = (v2f){sA, sA};
            const v2f inB2 = (v2f){ib, ib}, sB2 = (v2f){sB, sB};
            const v2f zero2 = (v2f)(0.0f);
            v2f accA = (v2f)(0.0f), accB = (v2f)(0.0f);

            #pragma unroll
            for (int q = 0; q < 16; ++q) {
                const float4 x = wxp[q];   // wx for units 4q..4q+3 (broadcast read)
                const float4 y = wyp[q];
                const float4 b = wbp[q];
                const float4 w = w2p[q];
                const v2f x0 = (v2f){x.x, x.y}, x1 = (v2f){x.z, x.w};
                const v2f y0 = (v2f){y.x, y.y}, y1 = (v2f){y.z, y.w};
                const v2f b0 = (v2f){b.x, b.y}, b1_ = (v2f){b.z, b.w};
                const v2f w0 = (v2f){w.x, w.y}, w1 = (v2f){w.z, w.w};

                v2f z;
                z = pk_fma(inA2, x0, pk_fma(sA2, y0, b0));
                z = __builtin_elementwise_max(z, zero2);
                accA = pk_fma(z, w0, accA);
                z = pk_fma(inA2, x1, pk_fma(sA2, y1, b1_));
                z = __builtin_elementwise_max(z, zero2);
                accA = pk_fma(z, w1, accA);

                z = pk_fma(inB2, x0, pk_fma(sB2, y0, b0));
                z = __builtin_elementwise_max(z, zero2);
                accB = pk_fma(z, w0, accB);
                z = pk_fma(inB2, x1, pk_fma(sB2, y1, b1_));
                z = __builtin_elementwise_max(z, zero2);
                accB = pk_fma(z, w1, accB);
            }

            float pa = accA.x + accA.y;
            pa = dpp_add<0xB1>(pa);
            pa = dpp_add<0x4E>(pa);
            const float ofA = pa + b2v;

            float pb = accB.x + accB.y;
            pb = dpp_add<0xB1>(pb);
            pb = dpp_add<0x4E>(pb);
            const float ofB = pb + b2v;

            sA = fmaf(DT, ia - ofA, sA);   // identical across the quad
            sB = fmaf(DT, ib - ofB, sB);

            if (p == 0) {
                *poA = ofA; *psA = sA;
                *poB = ofB; *psB = sB;
            }
            poA += batch; psA += batch;
            poB += batch; psB += batch;
        }

        #pragma unroll
        for (int r = 0; r < 4; ++r) { bufA[r] = nbA[r]; bufB[r] = nbB[r]; }
    }

    // Tail for iters % 4 != 0 (dead for iters=512, kept for generality).
    for (int t = tail_start; t < iters; ++t) {
        const float ia = inA[(size_t)t * batch], ib = inB[(size_t)t * batch];
        const v2f inA2 = (v2f){ia, ia}, sA2 = (v2f){sA, sA};
        const v2f inB2 = (v2f){ib, ib}, sB2 = (v2f){sB, sB};
        const v2f zero2 = (v2f)(0.0f);
        v2f accA = (v2f)(0.0f), accB = (v2f)(0.0f);
        #pragma unroll
        for (int q = 0; q < 16; ++q) {
            const float4 x = wxp[q], y = wyp[q], b = wbp[q], w = w2p[q];
            const v2f x0 = (v2f){x.x, x.y}, x1 = (v2f){x.z, x.w};
            const v2f y0 = (v2f){y.x, y.y}, y1 = (v2f){y.z, y.w};
            const v2f b0 = (v2f){b.x, b.y}, b1_ = (v2f){b.z, b.w};
            const v2f w0 = (v2f){w.x, w.y}, w1 = (v2f){w.z, w.w};
            v2f z;
            z = pk_fma(inA2, x0, pk_fma(sA2, y0, b0));
            z = __builtin_elementwise_max(z, zero2);
            accA = pk_fma(z, w0, accA);
            z = pk_fma(inA2, x1, pk_fma(sA2, y1, b1_));
            z = __builtin_elementwise_max(z, zero2);
            accA = pk_fma(z, w1, accA);
            z = pk_fma(inB2, x0, pk_fma(sB2, y0, b0));
            z = __builtin_elementwise_max(z, zero2);
            accB = pk_fma(z, w0, accB);
            z = pk_fma(inB2, x1, pk_fma(sB2, y1, b1_));
            z = __builtin_elementwise_max(z, zero2);
            accB = pk_fma(z, w1, accB);
        }
        float pa = accA.x + accA.y;
        pa = dpp_add<0xB1>(pa); pa = dpp_add<0x4E>(pa);
        const float ofA = pa + b2v;
        float pb = accB.x + accB.y;
        pb = dpp_add<0xB1>(pb); pb = dpp_add<0x4E>(pb);
        const float ofB = pb + b2v;
        sA = fmaf(DT, ia - ofA, sA);
        sB = fmaf(DT, ib - ofB, sB);
        if (p == 0) { *poA = ofA; *psA = sA; *poB = ofB; *psB = sB; }
        poA += batch; psA += batch;
        poB += batch; psB += batch;
    }
}

extern "C" void kernel_launch(void* const* d_in, const int* in_sizes, int n_in,
                              void* d_out, int out_size, void* d_ws, size_t ws_size,
                              hipStream_t stream) {
    const float* inflows  = (const float*)d_in[0];
    const float* storage0 = (const float*)d_in[1];
    const float* W1       = (const float*)d_in[2];
    const float* b1       = (const float*)d_in[3];
    const float* W2       = (const float*)d_in[4];
    const float* b2       = (const float*)d_in[5];

    int batch  = in_sizes[1];                 // 65536
    int iters  = in_sizes[0] / batch;         // 512
    int hidden = in_sizes[3];                 // 256

    float* out_storages = (float*)d_out;                                // (iters+1, batch)
    float* out_outflows = out_storages + (size_t)(iters + 1) * batch;   // (iters, batch)

    long long threads = (long long)(batch / 2) * 4;   // quad per element-pair
    waterbalance<<<(int)((threads + 255) / 256), 256, 0, stream>>>(
        inflows, storage0, W1, b1, W2, b2, out_storages, out_outflows,
        iters, batch, hidden);
}

// Round 9
// 1148.593 us; speedup vs baseline: 1.0202x; 1.0202x over previous
//
#include <hip/hip_runtime.h>

#define DT 0.1f

typedef float v2f __attribute__((ext_vector_type(2)));

// Pack per-hidden-unit weights into one float4: (W1[0][j], W1[1][j], b1[j], W2[j])
__global__ void pack_weights(const float* __restrict__ W1, const float* __restrict__ b1,
                             const float* __restrict__ W2, float4* __restrict__ ws, int hidden) {
    int j = blockIdx.x * blockDim.x + threadIdx.x;
    if (j < hidden) {
        ws[j] = make_float4(W1[j], W1[hidden + j], b1[j], W2[j]);
    }
}

// Guaranteed packed fp32 FMA (VOP3P; operands are 64-bit VGPR pairs).
__device__ __forceinline__ v2f pk_fma(v2f a, v2f b, v2f c) {
    v2f d;
    asm("v_pk_fma_f32 %0, %1, %2, %3" : "=v"(d) : "v"(a), "v"(b), "v"(c));
    return d;
}

// DPP-based add-reduce (VALU pipe). 0xB1=xor1, 0x4E=xor2, 0x141=half-mirror (8-lane fold).
template <int CTRL>
__device__ __forceinline__ float dpp_add(float x) {
    int v = __builtin_amdgcn_mov_dpp(__float_as_int(x), CTRL, 0xf, 0xf, true);
    return x + __int_as_float(v);
}

// p = tid&7 owns hidden units [p*32, (p+1)*32); each 8-lane group carries FOUR
// consecutive elements e0..e0+3. Weights (128 regs) get AGPR-parked (rounds 3-7:
// unavoidable); the q-outer/r-inner loop reads each weight register ONCE per
// step and uses it for 4 elements, amortizing the accvgpr-read tax 80% -> 20%.
__global__ __launch_bounds__(256, 2) void waterbalance(
    const float* __restrict__ inflows, const float* __restrict__ storage0,
    const float4* __restrict__ ws, const float* __restrict__ b2,
    float* __restrict__ out_storages, float* __restrict__ out_outflows,
    int iters, int batch)
{
    const int tid = blockIdx.x * blockDim.x + threadIdx.x;
    const int g = tid >> 3;          // element-quad id
    const int p = tid & 7;           // unit-block within element
    const int nquad = batch >> 2;
    if (g >= nquad) return;
    const int e0 = g << 2;           // four consecutive elements

    // This lane's 32 units' weights as v2f pairs: 64 v2f = 128 regs (AGPR-parked).
    v2f wx[16], wy[16], wb[16], w2[16];
    #pragma unroll
    for (int q = 0; q < 16; ++q) {
        float4 a = ws[p * 32 + 2 * q];
        float4 b = ws[p * 32 + 2 * q + 1];
        wx[q] = (v2f){a.x, b.x};
        wy[q] = (v2f){a.y, b.y};
        wb[q] = (v2f){a.z, b.z};
        w2[q] = (v2f){a.w, b.w};
    }
    // One-time opaque pin: prevents re-load-from-memory sinking (round 2 tell).
    #pragma unroll
    for (int q = 0; q < 16; ++q) {
        asm("" : "+v"(wx[q]), "+v"(wy[q]), "+v"(wb[q]), "+v"(w2[q]));
    }

    const float b2v = b2[0];

    float s[4], cur[4];
    #pragma unroll
    for (int r = 0; r < 4; ++r) s[r] = storage0[e0 + r];
    if (p == 0) {
        #pragma unroll
        for (int r = 0; r < 4; ++r) out_storages[e0 + r] = s[r];
    }
    #pragma unroll
    for (int r = 0; r < 4; ++r) cur[r] = inflows[e0 + r];

    for (int t = 0; t < iters; ++t) {
        // Prefetch next step's inflows (4 loads in flight over ~900cy compute).
        float nxt[4];
        if (t + 1 < iters) {
            const size_t bn = (size_t)(t + 1) * batch + e0;
            #pragma unroll
            for (int r = 0; r < 4; ++r) nxt[r] = inflows[bn + r];
        } else {
            #pragma unroll
            for (int r = 0; r < 4; ++r) nxt[r] = 0.0f;
        }

        const v2f zero2 = (v2f)(0.0f);
        v2f in2[4], s2[4], acc[4];
        #pragma unroll
        for (int r = 0; r < 4; ++r) {
            in2[r] = (v2f){cur[r], cur[r]};
            s2[r]  = (v2f){s[r], s[r]};
            acc[r] = zero2;
        }

        // q outer, r inner: each weight v2f fetched once, used for 4 elements.
        #pragma unroll
        for (int q = 0; q < 16; ++q) {
            const v2f x = wx[q], y = wy[q], bb = wb[q], w = w2[q];
            #pragma unroll
            for (int r = 0; r < 4; ++r) {
                v2f z = pk_fma(in2[r], x, pk_fma(s2[r], y, bb));
                z = __builtin_elementwise_max(z, zero2);
                acc[r] = pk_fma(z, w, acc[r]);
            }
        }

        float of[4];
        #pragma unroll
        for (int r = 0; r < 4; ++r) {
            float part = acc[r].x + acc[r].y;
            part = dpp_add<0xB1>(part);    // xor 1
            part = dpp_add<0x4E>(part);    // xor 2
            part = dpp_add<0x141>(part);   // fold the two quads of the 8-group
            of[r] = part + b2v;
            s[r] = fmaf(DT, cur[r] - of[r], s[r]);   // identical across the 8 lanes
        }

        if (p == 0) {
            const size_t ot = (size_t)t * batch + e0;
            const size_t st = (size_t)(t + 1) * batch + e0;
            #pragma unroll
            for (int r = 0; r < 4; ++r) {
                out_outflows[ot + r] = of[r];
                out_storages[st + r] = s[r];
            }
        }

        #pragma unroll
        for (int r = 0; r < 4; ++r) cur[r] = nxt[r];
    }
}

extern "C" void kernel_launch(void* const* d_in, const int* in_sizes, int n_in,
                              void* d_out, int out_size, void* d_ws, size_t ws_size,
                              hipStream_t stream) {
    const float* inflows  = (const float*)d_in[0];
    const float* storage0 = (const float*)d_in[1];
    const float* W1       = (const float*)d_in[2];
    const float* b1       = (const float*)d_in[3];
    const float* W2       = (const float*)d_in[4];
    const float* b2       = (const float*)d_in[5];

    int batch  = in_sizes[1];                 // 65536
    int iters  = in_sizes[0] / batch;         // 512
    int hidden = in_sizes[3];                 // 256

    float4* ws = (float4*)d_ws;
    pack_weights<<<(hidden + 255) / 256, 256, 0, stream>>>(W1, b1, W2, ws, hidden);

    float* out_storages = (float*)d_out;                                // (iters+1, batch)
    float* out_outflows = out_storages + (size_t)(iters + 1) * batch;   // (iters, batch)

    int threads = (batch / 4) * 8;            // 131072
    waterbalance<<<(threads + 255) / 256, 256, 0, stream>>>(
        inflows, storage0, ws, b2, out_storages, out_outflows, iters, batch);
}